// Round 3
// baseline (777.381 us; speedup 1.0000x reference)
//
#include <hip/hip_runtime.h>

#define NCAP 10     // capsule classes c
#define NB   256    // batch b
#define NN   1152   // route nodes n
#define KI   8      // input dim i
#define NO   16     // output dim o
#define NT   768    // threads per block (12 waves)
#define NWV  12
#define TB   2      // batches per block
#define NPASS 6     // n per 4-lane cluster = NN / (NT/4)
#define NCLUS 192   // clusters per block
#define NITER 3

__global__ __launch_bounds__(NT, 3) void capsule_kernel(
    const float* __restrict__ x,    // [256,1152,8]
    const float* __restrict__ w,    // [10,1152,8,16]
    float* __restrict__ out)        // [10,256,16]
{
    __shared__ float s_sp[NWV][TB][4][4];  // per-wave weighted-sum partials
    __shared__ float s_ls[NWV][TB];        // per-wave lsum partials (x4 dup)
    __shared__ float s_v[TB][NO];          // squashed v broadcast

    const int t    = threadIdx.x;
    const int wv   = t >> 6;
    const int lane = t & 63;
    const int j    = lane & 3;   // o-quad owned by this lane: o in [4j,4j+4)
    const int g    = t >> 2;     // cluster id in block, 0..191

    // XCD swizzle: 1280 % 8 == 0 -> bijective; same-c blocks share an XCD L2.
    const int bid = blockIdx.x;
    const int swz = (bid & 7) * (NCAP * (NB / TB) / 8) + (bid >> 3);
    const int c   = swz / (NB / TB);
    const int b0  = (swz % (NB / TB)) * TB;

    float prior[NPASS][TB][4];   // 48 regs
    float logit[NPASS][TB];      // 12 regs, thread-private (dup x4 per cluster)

    // ---- priors: cluster owns n = p*192 + g; lane j accumulates o-quad j ----
    #pragma unroll
    for (int p = 0; p < NPASS; ++p) {
        const int n = p * NCLUS + g;
        float xv[TB][KI];
        #pragma unroll
        for (int tb = 0; tb < TB; ++tb) {
            const float4* xp = reinterpret_cast<const float4*>(
                x + ((size_t)(b0 + tb) * NN + n) * KI);
            float4 x0 = xp[0], x1 = xp[1];   // same addr across cluster -> bcast
            xv[tb][0] = x0.x; xv[tb][1] = x0.y; xv[tb][2] = x0.z; xv[tb][3] = x0.w;
            xv[tb][4] = x1.x; xv[tb][5] = x1.y; xv[tb][6] = x1.z; xv[tb][7] = x1.w;
            logit[p][tb] = 0.f;
            prior[p][tb][0] = prior[p][tb][1] = prior[p][tb][2] = prior[p][tb][3] = 0.f;
        }
        const float4* wp = reinterpret_cast<const float4*>(
            w + ((size_t)c * NN + n) * (KI * NO));
        #pragma unroll
        for (int r = 0; r < KI; ++r) {
            float4 wq = wp[r * 4 + j];   // wave covers 16 full 64B lines/instr
            #pragma unroll
            for (int tb = 0; tb < TB; ++tb) {
                prior[p][tb][0] = fmaf(xv[tb][r], wq.x, prior[p][tb][0]);
                prior[p][tb][1] = fmaf(xv[tb][r], wq.y, prior[p][tb][1]);
                prior[p][tb][2] = fmaf(xv[tb][r], wq.z, prior[p][tb][2]);
                prior[p][tb][3] = fmaf(xv[tb][r], wq.w, prior[p][tb][3]);
            }
        }
    }

    for (int iter = 0; iter < NITER; ++iter) {
        // ---- fused exp + lsum + weighted-sum partials (no max-sub: |logit|
        // bounded ~30, exp exact-safe in f32, softmax ratio identical) ----
        float lsum[TB] = {0.f, 0.f};
        float sp[TB][4] = {{0.f,0.f,0.f,0.f},{0.f,0.f,0.f,0.f}};
        #pragma unroll
        for (int p = 0; p < NPASS; ++p) {
            #pragma unroll
            for (int tb = 0; tb < TB; ++tb) {
                float e = __expf(logit[p][tb]);
                lsum[tb] += e;
                sp[tb][0] = fmaf(e, prior[p][tb][0], sp[tb][0]);
                sp[tb][1] = fmaf(e, prior[p][tb][1], sp[tb][1]);
                sp[tb][2] = fmaf(e, prior[p][tb][2], sp[tb][2]);
                sp[tb][3] = fmaf(e, prior[p][tb][3], sp[tb][3]);
            }
        }
        // lsum: full-wave butterfly (each n counted 4x -> divide later)
        #pragma unroll
        for (int tb = 0; tb < TB; ++tb) {
            float s = lsum[tb];
            s += __shfl_xor(s, 1);  s += __shfl_xor(s, 2);
            s += __shfl_xor(s, 4);  s += __shfl_xor(s, 8);
            s += __shfl_xor(s, 16); s += __shfl_xor(s, 32);
            if (lane == 0) s_ls[wv][tb] = s;
        }
        // sp: sum across the wave's 16 clusters (lanes with equal j)
        #pragma unroll
        for (int tb = 0; tb < TB; ++tb) {
            #pragma unroll
            for (int e2 = 0; e2 < 4; ++e2) {
                float s = sp[tb][e2];
                s += __shfl_xor(s, 4);  s += __shfl_xor(s, 8);
                s += __shfl_xor(s, 16); s += __shfl_xor(s, 32);
                if (lane < 4) s_sp[wv][tb][lane][e2] = s;
            }
        }
        __syncthreads();

        // ---- finalize on 32 threads: combine waves, normalize, squash ----
        if (t < TB * NO) {
            const int tb = t >> 4, o = t & 15;
            float acc = 0.f, lt = 0.f;
            #pragma unroll
            for (int w2 = 0; w2 < NWV; ++w2) {
                acc += s_sp[w2][tb][o >> 2][o & 3];
                lt  += s_ls[w2][tb];
            }
            float s_o = 4.0f * acc / lt;   // undo 4x lsum duplication
            float sq = s_o * s_o;
            sq += __shfl_xor(sq, 1); sq += __shfl_xor(sq, 2);
            sq += __shfl_xor(sq, 4); sq += __shfl_xor(sq, 8);
            float scale = sq / ((1.f + sq) * sqrtf(sq));
            float vo = s_o * scale;
            s_v[tb][o] = vo;
            if (iter == NITER - 1)
                out[((size_t)c * NB + b0 + tb) * NO + o] = vo;
        }
        __syncthreads();

        // ---- logit update: 4 FMAs + 2 intra-cluster shuffles, no LDS RMW ----
        if (iter < NITER - 1) {
            float vv[TB][4];
            #pragma unroll
            for (int tb = 0; tb < TB; ++tb) {
                vv[tb][0] = s_v[tb][4 * j + 0];
                vv[tb][1] = s_v[tb][4 * j + 1];
                vv[tb][2] = s_v[tb][4 * j + 2];
                vv[tb][3] = s_v[tb][4 * j + 3];
            }
            #pragma unroll
            for (int p = 0; p < NPASS; ++p) {
                #pragma unroll
                for (int tb = 0; tb < TB; ++tb) {
                    float d = prior[p][tb][0] * vv[tb][0];
                    d = fmaf(prior[p][tb][1], vv[tb][1], d);
                    d = fmaf(prior[p][tb][2], vv[tb][2], d);
                    d = fmaf(prior[p][tb][3], vv[tb][3], d);
                    d += __shfl_xor(d, 1);   // sum the cluster's 4 o-quads
                    d += __shfl_xor(d, 2);
                    logit[p][tb] += d;
                }
            }
        }
    }
}

extern "C" void kernel_launch(void* const* d_in, const int* in_sizes, int n_in,
                              void* d_out, int out_size, void* d_ws, size_t ws_size,
                              hipStream_t stream) {
    const float* x = (const float*)d_in[0];
    const float* w = (const float*)d_in[1];
    float* out = (float*)d_out;
    capsule_kernel<<<dim3(NCAP * (NB / TB)), dim3(NT), 0, stream>>>(x, w, out);
}

// Round 4
// 188.055 us; speedup vs baseline: 4.1338x; 4.1338x over previous
//
#include <hip/hip_runtime.h>

#define NCAP 10     // capsule classes c
#define NB   256    // batch b
#define NN   1152   // route nodes n
#define KI   8      // input dim i
#define NO   16     // output dim o
#define NT   512    // threads per block (8 waves)
#define NWV  8
#define TB   2      // batches per block
#define NG   32     // ng groups (n = nl*32 + ng)
#define NPT  36     // n per thread
#define NITER 3

__global__ __launch_bounds__(NT, 4) void capsule_kernel(
    const float* __restrict__ x,    // [256,1152,8]
    const float* __restrict__ w,    // [10,1152,8,16]
    float* __restrict__ out)        // [10,256,16]
{
    __shared__ float s_x0[NN * KI];        // 36 KB: x[b0]
    __shared__ float s_logit[TB][NN];      // 9 KB
    __shared__ float s_red[NWV][TB];       // lsum partials
    __shared__ float s_red2[NWV][TB][NO];  // sp partials
    __shared__ float s_v[TB][NO];

    const int t    = threadIdx.x;
    const int wv   = t >> 6;
    const int lane = t & 63;
    const int o    = t & 15;         // output component owned by lane
    const int ng   = t >> 4;         // 0..31

    // XCD swizzle: 1280 % 8 == 0 -> bijective; same-c blocks share an XCD L2.
    const int bid = blockIdx.x;
    const int swz = (bid & 7) * (NCAP * (NB / TB) / 8) + (bid >> 3);
    const int c   = swz / (NB / TB);
    const int b0  = (swz % (NB / TB)) * TB;

    // stage x[b0] into LDS; zero logits
    {
        const float4* xs = reinterpret_cast<const float4*>(x + (size_t)b0 * NN * KI);
        float4* xd = reinterpret_cast<float4*>(s_x0);
        #pragma unroll
        for (int k = 0; k < 5; ++k) {
            int idx = t + NT * k;
            if (idx < NN * KI / 4) xd[idx] = xs[idx];
        }
        float* lg = &s_logit[0][0];
        #pragma unroll
        for (int k = 0; k < 5; ++k) {
            int idx = t + NT * k;
            if (idx < TB * NN) lg[idx] = 0.f;
        }
    }
    __syncthreads();

    // ---- priors: small per-n footprint (round-1 shape), W loaded once,
    // used for both batches ----
    float prior[NPT][TB];
    #pragma unroll
    for (int nl = 0; nl < NPT; ++nl) {
        const int n = nl * NG + ng;
        const float* wp = w + (((size_t)c * NN + n) * KI) * NO + o;
        const float4* x1p = reinterpret_cast<const float4*>(
            x + ((size_t)(b0 + 1) * NN + n) * KI);
        float4 xa = x1p[0], xb = x1p[1];   // broadcast across 16 o-lanes (L1)
        float x1v[KI] = {xa.x, xa.y, xa.z, xa.w, xb.x, xb.y, xb.z, xb.w};
        float a0 = 0.f, a1 = 0.f;
        #pragma unroll
        for (int i = 0; i < KI; ++i) {
            float wq = wp[i * NO];
            a0 = fmaf(s_x0[n * KI + i], wq, a0);
            a1 = fmaf(x1v[i], wq, a1);
        }
        prior[nl][0] = a0;
        prior[nl][1] = a1;
    }

    for (int iter = 0; iter < NITER; ++iter) {
        // ---- fused exp + lsum + weighted-sum partial (no max-sub: |logit|
        // bounded ~30, fp32 exp exact-safe, softmax ratio identical) ----
        float lsum[TB] = {0.f, 0.f};
        float sp[TB]   = {0.f, 0.f};
        #pragma unroll
        for (int nl = 0; nl < NPT; ++nl) {
            const int n = nl * NG + ng;
            #pragma unroll
            for (int tb = 0; tb < TB; ++tb) {
                float e = __expf(s_logit[tb][n]);
                lsum[tb] += e;
                sp[tb] = fmaf(e, prior[nl][tb], sp[tb]);
            }
        }
        #pragma unroll
        for (int tb = 0; tb < TB; ++tb) {
            float s = lsum[tb];
            s += __shfl_xor(s, 1);  s += __shfl_xor(s, 2);
            s += __shfl_xor(s, 4);  s += __shfl_xor(s, 8);
            s += __shfl_xor(s, 16); s += __shfl_xor(s, 32);
            if (lane == 0) s_red[wv][tb] = s;   // = 16 x (partial true lsum)
            float p = sp[tb];
            p += __shfl_xor(p, 16); p += __shfl_xor(p, 32);  // sum 4 ngs
            if (lane < NO) s_red2[wv][tb][lane] = p;
        }
        __syncthreads();

        // ---- finalize on 32 threads: combine waves, normalize, squash ----
        if (t < TB * NO) {
            const int tb = t >> 4, oc = t & 15;
            float acc = 0.f, lt = 0.f;
            #pragma unroll
            for (int w2 = 0; w2 < NWV; ++w2) {
                acc += s_red2[w2][tb][oc];
                lt  += s_red[w2][tb];
            }
            float s_o = 16.0f * acc / lt;     // undo 16x o-duplication in lsum
            float sq = s_o * s_o;
            sq += __shfl_xor(sq, 1); sq += __shfl_xor(sq, 2);
            sq += __shfl_xor(sq, 4); sq += __shfl_xor(sq, 8);
            float scale = sq / ((1.f + sq) * sqrtf(sq));
            float vo = s_o * scale;
            s_v[tb][oc] = vo;
            if (iter == NITER - 1)
                out[((size_t)c * NB + b0 + tb) * NO + oc] = vo;
        }
        __syncthreads();

        // ---- logit update: butterfly over the 16 o-lanes, one writer ----
        if (iter < NITER - 1) {
            const float v0 = s_v[0][o];
            const float v1 = s_v[1][o];
            #pragma unroll
            for (int nl = 0; nl < NPT; ++nl) {
                const int n = nl * NG + ng;
                float d0 = prior[nl][0] * v0;
                d0 += __shfl_xor(d0, 1); d0 += __shfl_xor(d0, 2);
                d0 += __shfl_xor(d0, 4); d0 += __shfl_xor(d0, 8);
                float d1 = prior[nl][1] * v1;
                d1 += __shfl_xor(d1, 1); d1 += __shfl_xor(d1, 2);
                d1 += __shfl_xor(d1, 4); d1 += __shfl_xor(d1, 8);
                if (o == 0) {
                    s_logit[0][n] += d0;
                    s_logit[1][n] += d1;
                }
            }
            __syncthreads();
        }
    }
}

extern "C" void kernel_launch(void* const* d_in, const int* in_sizes, int n_in,
                              void* d_out, int out_size, void* d_ws, size_t ws_size,
                              hipStream_t stream) {
    const float* x = (const float*)d_in[0];
    const float* w = (const float*)d_in[1];
    float* out = (float*)d_out;
    capsule_kernel<<<dim3(NCAP * (NB / TB)), dim3(NT), 0, stream>>>(x, w, out);
}

// Round 5
// 161.451 us; speedup vs baseline: 4.8150x; 1.1648x over previous
//
#include <hip/hip_runtime.h>

#define NCAP 10     // capsule classes c
#define NB   256    // batch b
#define NN   1152   // route nodes n
#define KI   8      // input dim i
#define NO   16     // output dim o
#define NT   512    // threads per block (8 waves)
#define NWV  8
#define TB   2      // batches per block
#define NG   32     // ng groups (n = nl*32 + ng)
#define NPT  36     // n per thread
#define NITER 3

// NOTE: no min-waves arg — __launch_bounds__(512,4) clamped VGPRs to 64 and
// spilled the 72-float prior array (round 4: 87 MB scratch writes). Unclamped,
// the unified VGPR/AGPR file holds it spill-free (round 1 evidence).
__global__ __launch_bounds__(NT) void capsule_kernel(
    const float* __restrict__ x,    // [256,1152,8]
    const float* __restrict__ w,    // [10,1152,8,16]
    float* __restrict__ out)        // [10,256,16]
{
    __shared__ float s_x0[NN * KI];        // 36 KB: x[b0]
    __shared__ float s_logit[TB][NN];      // 9 KB
    __shared__ float s_red[NWV][TB];       // lsum partials
    __shared__ float s_red2[NWV][TB][NO];  // sp partials
    __shared__ float s_v[TB][NO];

    const int t    = threadIdx.x;
    const int wv   = t >> 6;
    const int lane = t & 63;
    const int o    = t & 15;         // output component owned by lane
    const int ng   = t >> 4;         // 0..31

    // XCD swizzle: 1280 % 8 == 0 -> bijective; same-c blocks share an XCD L2.
    const int bid = blockIdx.x;
    const int swz = (bid & 7) * (NCAP * (NB / TB) / 8) + (bid >> 3);
    const int c   = swz / (NB / TB);
    const int b0  = (swz % (NB / TB)) * TB;

    // stage x[b0] into LDS; zero logits
    {
        const float4* xs = reinterpret_cast<const float4*>(x + (size_t)b0 * NN * KI);
        float4* xd = reinterpret_cast<float4*>(s_x0);
        #pragma unroll
        for (int k = 0; k < 5; ++k) {
            int idx = t + NT * k;
            if (idx < NN * KI / 4) xd[idx] = xs[idx];
        }
        float* lg = &s_logit[0][0];
        #pragma unroll
        for (int k = 0; k < 5; ++k) {
            int idx = t + NT * k;
            if (idx < TB * NN) lg[idx] = 0.f;
        }
    }
    __syncthreads();

    // ---- priors: small per-n footprint, W loaded once, used for both b ----
    float prior[NPT][TB];
    #pragma unroll
    for (int nl = 0; nl < NPT; ++nl) {
        const int n = nl * NG + ng;
        const float* wp = w + (((size_t)c * NN + n) * KI) * NO + o;
        const float4* x1p = reinterpret_cast<const float4*>(
            x + ((size_t)(b0 + 1) * NN + n) * KI);
        float4 xa = x1p[0], xb = x1p[1];   // broadcast across 16 o-lanes (L1)
        float x1v[KI] = {xa.x, xa.y, xa.z, xa.w, xb.x, xb.y, xb.z, xb.w};
        float a0 = 0.f, a1 = 0.f;
        #pragma unroll
        for (int i = 0; i < KI; ++i) {
            float wq = wp[i * NO];
            a0 = fmaf(s_x0[n * KI + i], wq, a0);
            a1 = fmaf(x1v[i], wq, a1);
        }
        prior[nl][0] = a0;
        prior[nl][1] = a1;
    }

    for (int iter = 0; iter < NITER; ++iter) {
        // ---- fused exp + lsum + weighted-sum partial (no max-sub: |logit|
        // bounded ~30, fp32 exp exact-safe, softmax ratio identical) ----
        float lsum[TB] = {0.f, 0.f};
        float sp[TB]   = {0.f, 0.f};
        #pragma unroll
        for (int nl = 0; nl < NPT; ++nl) {
            const int n = nl * NG + ng;
            #pragma unroll
            for (int tb = 0; tb < TB; ++tb) {
                float e = __expf(s_logit[tb][n]);
                lsum[tb] += e;
                sp[tb] = fmaf(e, prior[nl][tb], sp[tb]);
            }
        }
        #pragma unroll
        for (int tb = 0; tb < TB; ++tb) {
            float s = lsum[tb];
            s += __shfl_xor(s, 1);  s += __shfl_xor(s, 2);
            s += __shfl_xor(s, 4);  s += __shfl_xor(s, 8);
            s += __shfl_xor(s, 16); s += __shfl_xor(s, 32);
            if (lane == 0) s_red[wv][tb] = s;   // = 16 x (partial true lsum)
            float p = sp[tb];
            p += __shfl_xor(p, 16); p += __shfl_xor(p, 32);  // sum 4 ngs
            if (lane < NO) s_red2[wv][tb][lane] = p;
        }
        __syncthreads();

        // ---- finalize on 32 threads: combine waves, normalize, squash ----
        if (t < TB * NO) {
            const int tb = t >> 4, oc = t & 15;
            float acc = 0.f, lt = 0.f;
            #pragma unroll
            for (int w2 = 0; w2 < NWV; ++w2) {
                acc += s_red2[w2][tb][oc];
                lt  += s_red[w2][tb];
            }
            float s_o = 16.0f * acc / lt;     // undo 16x o-duplication in lsum
            float sq = s_o * s_o;
            sq += __shfl_xor(sq, 1); sq += __shfl_xor(sq, 2);
            sq += __shfl_xor(sq, 4); sq += __shfl_xor(sq, 8);
            float scale = sq / ((1.f + sq) * sqrtf(sq));
            float vo = s_o * scale;
            s_v[tb][oc] = vo;
            if (iter == NITER - 1)
                out[((size_t)c * NB + b0 + tb) * NO + oc] = vo;
        }
        __syncthreads();

        // ---- logit update: butterfly over the 16 o-lanes, one writer ----
        if (iter < NITER - 1) {
            const float v0 = s_v[0][o];
            const float v1 = s_v[1][o];
            #pragma unroll
            for (int nl = 0; nl < NPT; ++nl) {
                const int n = nl * NG + ng;
                float d0 = prior[nl][0] * v0;
                d0 += __shfl_xor(d0, 1); d0 += __shfl_xor(d0, 2);
                d0 += __shfl_xor(d0, 4); d0 += __shfl_xor(d0, 8);
                float d1 = prior[nl][1] * v1;
                d1 += __shfl_xor(d1, 1); d1 += __shfl_xor(d1, 2);
                d1 += __shfl_xor(d1, 4); d1 += __shfl_xor(d1, 8);
                if (o == 0) {
                    s_logit[0][n] += d0;
                    s_logit[1][n] += d1;
                }
            }
            __syncthreads();
        }
    }
}

extern "C" void kernel_launch(void* const* d_in, const int* in_sizes, int n_in,
                              void* d_out, int out_size, void* d_ws, size_t ws_size,
                              hipStream_t stream) {
    const float* x = (const float*)d_in[0];
    const float* w = (const float*)d_in[1];
    float* out = (float*)d_out;
    capsule_kernel<<<dim3(NCAP * (NB / TB)), dim3(NT), 0, stream>>>(x, w, out);
}

// Round 6
// 151.407 us; speedup vs baseline: 5.1344x; 1.0663x over previous
//
#include <hip/hip_runtime.h>

#define NCAP 10     // capsule classes c
#define NB   256    // batch b
#define NN   1152   // route nodes n
#define KI   8      // input dim i
#define NO   16     // output dim o
#define NT   576    // threads per block (9 waves)
#define NWV  9
#define TB   2      // batches per block
#define NPT  2      // n per thread (contiguous pair)
#define NITER 3

__global__ __launch_bounds__(NT) void capsule_kernel(
    const float* __restrict__ x,    // [256,1152,8]
    const float* __restrict__ w,    // [10,1152,8,16]
    float* __restrict__ out)        // [10,256,16]
{
    __shared__ float s_sp[NWV][TB][NO];   // per-wave component sums
    __shared__ float s_ls[NWV][TB];       // per-wave lsum
    __shared__ float s_v[TB][NO];         // squashed v broadcast

    const int t    = threadIdx.x;
    const int wv   = t >> 6;
    const int lane = t & 63;

    // XCD swizzle: 1280 % 8 == 0 -> bijective; same-c blocks share an XCD L2.
    const int bid = blockIdx.x;
    const int swz = (bid & 7) * (NCAP * (NB / TB) / 8) + (bid >> 3);
    const int c   = swz / (NB / TB);
    const int b0  = (swz % (NB / TB)) * TB;

    const int n0 = t * NPT;   // this thread's first n

    // ---- load x for both batches: 16 floats each (fully coalesced) ----
    float xr[TB][NPT * KI];
    #pragma unroll
    for (int tb = 0; tb < TB; ++tb) {
        const float4* xp = reinterpret_cast<const float4*>(
            x + ((size_t)(b0 + tb) * NN + n0) * KI);
        #pragma unroll
        for (int k = 0; k < 4; ++k) {
            float4 q = xp[k];
            xr[tb][4*k+0] = q.x; xr[tb][4*k+1] = q.y;
            xr[tb][4*k+2] = q.z; xr[tb][4*k+3] = q.w;
        }
    }

    // ---- priors: prior[n][tb][o]; W loaded once, used for both batches ----
    float prior[NPT][TB][NO];
    #pragma unroll
    for (int n = 0; n < NPT; ++n)
        #pragma unroll
        for (int tb = 0; tb < TB; ++tb)
            #pragma unroll
            for (int o = 0; o < NO; ++o) prior[n][tb][o] = 0.f;

    {
        const float4* wp = reinterpret_cast<const float4*>(
            w + ((size_t)c * NN + n0) * (KI * NO));
        #pragma unroll
        for (int n = 0; n < NPT; ++n)
            #pragma unroll
            for (int i = 0; i < KI; ++i)
                #pragma unroll
                for (int jq = 0; jq < 4; ++jq) {
                    float4 wq = wp[n * 32 + i * 4 + jq];
                    #pragma unroll
                    for (int tb = 0; tb < TB; ++tb) {
                        float xs = xr[tb][n * KI + i];
                        prior[n][tb][4*jq+0] = fmaf(xs, wq.x, prior[n][tb][4*jq+0]);
                        prior[n][tb][4*jq+1] = fmaf(xs, wq.y, prior[n][tb][4*jq+1]);
                        prior[n][tb][4*jq+2] = fmaf(xs, wq.z, prior[n][tb][4*jq+2]);
                        prior[n][tb][4*jq+3] = fmaf(xs, wq.w, prior[n][tb][4*jq+3]);
                    }
                }
    }

    float logit[NPT][TB] = {{0.f, 0.f}, {0.f, 0.f}};

    const int bl0 = lane & 1, bl1 = (lane >> 1) & 1,
              bl2 = (lane >> 2) & 1, bl3 = (lane >> 3) & 1;

    for (int iter = 0; iter < NITER; ++iter) {
        // ---- fused exp + lsum + weighted-sum (no max-sub: |logit| bounded
        // ~25, fp32 exp exact-safe, softmax ratio identical) ----
        float ls[TB] = {0.f, 0.f};
        float sp[TB][NO];
        #pragma unroll
        for (int tb = 0; tb < TB; ++tb)
            #pragma unroll
            for (int o = 0; o < NO; ++o) sp[tb][o] = 0.f;
        #pragma unroll
        for (int n = 0; n < NPT; ++n)
            #pragma unroll
            for (int tb = 0; tb < TB; ++tb) {
                float e = __expf(logit[n][tb]);
                ls[tb] += e;
                #pragma unroll
                for (int o = 0; o < NO; ++o)
                    sp[tb][o] = fmaf(e, prior[n][tb][o], sp[tb][o]);
            }

        // ---- comp-halving fold: 16 comps across each 16-lane group in 15
        // shuffles; lane ends holding comp (lane&15); then xor16/32 ----
        float g1[TB];
        #pragma unroll
        for (int tb = 0; tb < TB; ++tb) {
            float g8[8];
            #pragma unroll
            for (int r = 0; r < 8; ++r) {
                float keep = bl0 ? sp[tb][2*r+1] : sp[tb][2*r];
                float send = bl0 ? sp[tb][2*r]   : sp[tb][2*r+1];
                g8[r] = keep + __shfl_xor(send, 1);
            }
            float g4[4];
            #pragma unroll
            for (int r = 0; r < 4; ++r) {
                float keep = bl1 ? g8[2*r+1] : g8[2*r];
                float send = bl1 ? g8[2*r]   : g8[2*r+1];
                g4[r] = keep + __shfl_xor(send, 2);
            }
            float g2[2];
            #pragma unroll
            for (int r = 0; r < 2; ++r) {
                float keep = bl2 ? g4[2*r+1] : g4[2*r];
                float send = bl2 ? g4[2*r]   : g4[2*r+1];
                g2[r] = keep + __shfl_xor(send, 4);
            }
            {
                float keep = bl3 ? g2[1] : g2[0];
                float send = bl3 ? g2[0] : g2[1];
                g1[tb] = keep + __shfl_xor(send, 8);
            }
            g1[tb] += __shfl_xor(g1[tb], 16);
            g1[tb] += __shfl_xor(g1[tb], 32);

            float s = ls[tb];
            s += __shfl_xor(s, 1);  s += __shfl_xor(s, 2);
            s += __shfl_xor(s, 4);  s += __shfl_xor(s, 8);
            s += __shfl_xor(s, 16); s += __shfl_xor(s, 32);
            ls[tb] = s;
        }
        if (lane < NO) {
            s_sp[wv][0][lane] = g1[0];
            s_sp[wv][1][lane] = g1[1];
        }
        if (lane == 0) {
            s_ls[wv][0] = ls[0];
            s_ls[wv][1] = ls[1];
        }
        __syncthreads();

        // ---- finalize on 32 threads: combine waves, normalize, squash ----
        if (t < TB * NO) {
            const int tb = t >> 4, oc = t & 15;
            float acc = 0.f, lt = 0.f;
            #pragma unroll
            for (int w2 = 0; w2 < NWV; ++w2) {
                acc += s_sp[w2][tb][oc];
                lt  += s_ls[w2][tb];
            }
            float s_o = acc / lt;
            float sq = s_o * s_o;
            sq += __shfl_xor(sq, 1); sq += __shfl_xor(sq, 2);
            sq += __shfl_xor(sq, 4); sq += __shfl_xor(sq, 8);
            float scale = sq / ((1.f + sq) * sqrtf(sq));
            float vo = s_o * scale;
            s_v[tb][oc] = vo;
            if (iter == NITER - 1)
                out[((size_t)c * NB + b0 + tb) * NO + oc] = vo;
        }
        __syncthreads();

        // ---- logit update: fully thread-private, zero cross-lane ops ----
        if (iter < NITER - 1) {
            float vr[TB][NO];
            #pragma unroll
            for (int tb = 0; tb < TB; ++tb) {
                const float4* vp = reinterpret_cast<const float4*>(&s_v[tb][0]);
                #pragma unroll
                for (int k = 0; k < 4; ++k) {
                    float4 q = vp[k];
                    vr[tb][4*k+0] = q.x; vr[tb][4*k+1] = q.y;
                    vr[tb][4*k+2] = q.z; vr[tb][4*k+3] = q.w;
                }
            }
            #pragma unroll
            for (int n = 0; n < NPT; ++n)
                #pragma unroll
                for (int tb = 0; tb < TB; ++tb) {
                    float d = 0.f;
                    #pragma unroll
                    for (int o = 0; o < NO; ++o)
                        d = fmaf(prior[n][tb][o], vr[tb][o], d);
                    logit[n][tb] += d;
                }
        }
    }
}

extern "C" void kernel_launch(void* const* d_in, const int* in_sizes, int n_in,
                              void* d_out, int out_size, void* d_ws, size_t ws_size,
                              hipStream_t stream) {
    const float* x = (const float*)d_in[0];
    const float* w = (const float*)d_in[1];
    float* out = (float*)d_out;
    capsule_kernel<<<dim3(NCAP * (NB / TB)), dim3(NT), 0, stream>>>(x, w, out);
}

// Round 7
// 84.413 us; speedup vs baseline: 9.2092x; 1.7936x over previous
//
#include <hip/hip_runtime.h>

#define NCAP 10     // capsule classes c
#define NB   256    // batch b
#define NN   1152   // route nodes n
#define KI   8      // input dim i
#define NO   16     // output dim o
#define NT   1024   // threads per block (16 waves)
#define NWV  16
#define TB   2      // batches per block
#define NITER 3

__global__ __launch_bounds__(NT) void capsule_kernel(
    const float* __restrict__ x,    // [256,1152,8]
    const float* __restrict__ w,    // [10,1152,8,16]
    float* __restrict__ out)        // [10,256,16]
{
    // priors in LDS = software-managed spill space (reg variant capped at 3
    // waves/SIMD). XOR-swizzled at float4 granularity: quad q of row n lives
    // at 4*(q ^ ((n>>1)&3)); with 16(n&1) row parity this spreads 8
    // consecutive rows over all 32 banks -> 2 lanes/bank (free).
    __shared__ float s_prior[TB * NN * NO];   // 144 KB
    __shared__ float s_red2[NWV][TB][NO];     // per-wave comp partials
    __shared__ float s_ls[NWV][TB];           // per-wave exp-sum partials
    __shared__ float s_v[TB][NO];             // squashed v broadcast

    const int t    = threadIdx.x;
    const int wv   = t >> 6;
    const int lane = t & 63;
    const int j    = t & 3;        // build: o-quad owned by this lane
    const int g    = t >> 2;       // build: cluster id, 0..255

    // XCD swizzle: 1280 % 8 == 0 -> bijective; same-c blocks share an XCD L2.
    const int bid = blockIdx.x;
    const int swz = (bid & 7) * (NCAP * (NB / TB) / 8) + (bid >> 3);
    const int c   = swz / (NB / TB);
    const int b0  = (swz % (NB / TB)) * TB;

    const int bl0 = lane & 1, bl1 = (lane >> 1) & 1,
              bl2 = (lane >> 2) & 1, bl3 = (lane >> 3) & 1;

    // iter-1 weighted sum (softmax(0) is uniform -> just sum priors) is
    // accumulated during build: bs[tb][k] = this lane's o-quad partial.
    float bs[TB][4] = {{0.f,0.f,0.f,0.f},{0.f,0.f,0.f,0.f}};

    // ---- build: cluster (4 lanes) per n; lane j loads W o-quad j ----
    // W loads: instr (fixed i): lane 4g+j reads 512g + 64i + 16j ->
    // 16 complete contiguous 64B lines per instruction (100% density).
    auto build_round = [&](int n) {
        const float4* wp = reinterpret_cast<const float4*>(
            w + ((size_t)c * NN + n) * (KI * NO));
        float xs[TB][KI];
        #pragma unroll
        for (int tb = 0; tb < TB; ++tb) {
            const float4* xp = reinterpret_cast<const float4*>(
                x + ((size_t)(b0 + tb) * NN + n) * KI);
            float4 a = xp[0], b = xp[1];   // same addr across cluster -> bcast
            xs[tb][0]=a.x; xs[tb][1]=a.y; xs[tb][2]=a.z; xs[tb][3]=a.w;
            xs[tb][4]=b.x; xs[tb][5]=b.y; xs[tb][6]=b.z; xs[tb][7]=b.w;
        }
        float acc[TB][4] = {{0.f,0.f,0.f,0.f},{0.f,0.f,0.f,0.f}};
        #pragma unroll
        for (int i = 0; i < KI; ++i) {
            float4 wq = wp[i * 4 + j];
            #pragma unroll
            for (int tb = 0; tb < TB; ++tb) {
                acc[tb][0] = fmaf(xs[tb][i], wq.x, acc[tb][0]);
                acc[tb][1] = fmaf(xs[tb][i], wq.y, acc[tb][1]);
                acc[tb][2] = fmaf(xs[tb][i], wq.z, acc[tb][2]);
                acc[tb][3] = fmaf(xs[tb][i], wq.w, acc[tb][3]);
            }
        }
        const int pq = 4 * (j ^ ((n >> 1) & 3));
        #pragma unroll
        for (int tb = 0; tb < TB; ++tb) {
            bs[tb][0] += acc[tb][0]; bs[tb][1] += acc[tb][1];
            bs[tb][2] += acc[tb][2]; bs[tb][3] += acc[tb][3];
            *reinterpret_cast<float4*>(&s_prior[tb * (NN*NO) + n * NO + pq]) =
                make_float4(acc[tb][0], acc[tb][1], acc[tb][2], acc[tb][3]);
        }
    };
    #pragma unroll 1
    for (int r = 0; r < 4; ++r) build_round(r * 256 + g);
    if (g < 128) build_round(1024 + g);      // wave-uniform (t < 512)

    // reduce bs across the wave's 16 clusters (same j): lanes 0..3 write
    #pragma unroll
    for (int tb = 0; tb < TB; ++tb)
        #pragma unroll
        for (int k = 0; k < 4; ++k) {
            float s = bs[tb][k];
            s += __shfl_xor(s, 4);  s += __shfl_xor(s, 8);
            s += __shfl_xor(s, 16); s += __shfl_xor(s, 32);
            bs[tb][k] = s;
        }
    if (lane < 4) {
        #pragma unroll
        for (int tb = 0; tb < TB; ++tb) {
            s_red2[wv][tb][4*lane+0] = bs[tb][0];
            s_red2[wv][tb][4*lane+1] = bs[tb][1];
            s_red2[wv][tb][4*lane+2] = bs[tb][2];
            s_red2[wv][tb][4*lane+3] = bs[tb][3];
        }
    }
    __syncthreads();

    // ---- finalize: combine waves, softmax-normalize, squash ----
    auto finalize = [&](int iter) {
        if (t < TB * NO) {
            const int tb = t >> 4, oc = t & 15;
            float acc = 0.f, lt = 0.f;
            #pragma unroll
            for (int w2 = 0; w2 < NWV; ++w2) {
                acc += s_red2[w2][tb][oc];
                if (iter > 0) lt += s_ls[w2][tb];
            }
            if (iter == 0) lt = (float)NN;   // softmax(0) is uniform
            float s_o = acc / lt;
            float sq = s_o * s_o;
            sq += __shfl_xor(sq, 1); sq += __shfl_xor(sq, 2);
            sq += __shfl_xor(sq, 4); sq += __shfl_xor(sq, 8);
            float scale = sq / ((1.f + sq) * sqrtf(sq));
            float vo = s_o * scale;
            s_v[tb][oc] = vo;
            if (iter == NITER - 1)
                out[((size_t)c * NB + b0 + tb) * NO + oc] = vo;
        }
    };

    // consumption partition: thread owns n=t (and 1024+t if t<128) ->
    // logits fully thread-private; delta + exp + weighted-sum fused in ONE
    // LDS pass over the priors.
    float logit[2][TB] = {{0.f,0.f},{0.f,0.f}};

    auto routing_pass = [&]() {
        #pragma unroll
        for (int tb = 0; tb < TB; ++tb) {
            float vv[NO];
            {
                const float4* vp = reinterpret_cast<const float4*>(&s_v[tb][0]);
                float4 a = vp[0], b = vp[1], cc = vp[2], d4 = vp[3];
                vv[0]=a.x;  vv[1]=a.y;  vv[2]=a.z;  vv[3]=a.w;
                vv[4]=b.x;  vv[5]=b.y;  vv[6]=b.z;  vv[7]=b.w;
                vv[8]=cc.x; vv[9]=cc.y; vv[10]=cc.z; vv[11]=cc.w;
                vv[12]=d4.x; vv[13]=d4.y; vv[14]=d4.z; vv[15]=d4.w;
            }
            float sp[NO];
            #pragma unroll
            for (int o = 0; o < NO; ++o) sp[o] = 0.f;
            float lse = 0.f;
            #pragma unroll
            for (int rr = 0; rr < 2; ++rr) {
                if (rr == 1 && t >= 128) continue;   // wave-uniform
                const int n = rr * 1024 + t;
                float row[NO];
                #pragma unroll
                for (int q = 0; q < 4; ++q) {
                    const int off = tb * (NN*NO) + n * NO + 4 * (q ^ ((n >> 1) & 3));
                    float4 rq = *reinterpret_cast<const float4*>(&s_prior[off]);
                    row[4*q+0]=rq.x; row[4*q+1]=rq.y; row[4*q+2]=rq.z; row[4*q+3]=rq.w;
                }
                float d = 0.f;
                #pragma unroll
                for (int o = 0; o < NO; ++o) d = fmaf(row[o], vv[o], d);
                logit[rr][tb] += d;                  // |logit| <~ 30: fp32 exact-safe
                float e = __expf(logit[rr][tb]);
                lse += e;
                #pragma unroll
                for (int o = 0; o < NO; ++o) sp[o] = fmaf(e, row[o], sp[o]);
            }
            // exp-sum: full-wave butterfly
            float s = lse;
            s += __shfl_xor(s, 1);  s += __shfl_xor(s, 2);
            s += __shfl_xor(s, 4);  s += __shfl_xor(s, 8);
            s += __shfl_xor(s, 16); s += __shfl_xor(s, 32);
            if (lane == 0) s_ls[wv][tb] = s;
            // comp-halving fold: 16 comps over 16-lane groups in 15 shuffles,
            // then xor16/32 (proved correct in round 6)
            float g8[8];
            #pragma unroll
            for (int r = 0; r < 8; ++r) {
                float keep = bl0 ? sp[2*r+1] : sp[2*r];
                float send = bl0 ? sp[2*r]   : sp[2*r+1];
                g8[r] = keep + __shfl_xor(send, 1);
            }
            float g4[4];
            #pragma unroll
            for (int r = 0; r < 4; ++r) {
                float keep = bl1 ? g8[2*r+1] : g8[2*r];
                float send = bl1 ? g8[2*r]   : g8[2*r+1];
                g4[r] = keep + __shfl_xor(send, 2);
            }
            float g2[2];
            #pragma unroll
            for (int r = 0; r < 2; ++r) {
                float keep = bl2 ? g4[2*r+1] : g4[2*r];
                float send = bl2 ? g4[2*r]   : g4[2*r+1];
                g2[r] = keep + __shfl_xor(send, 4);
            }
            float g1;
            {
                float keep = bl3 ? g2[1] : g2[0];
                float send = bl3 ? g2[0] : g2[1];
                g1 = keep + __shfl_xor(send, 8);
            }
            g1 += __shfl_xor(g1, 16);
            g1 += __shfl_xor(g1, 32);
            if (lane < NO) s_red2[wv][tb][lane] = g1;
        }
    };

    finalize(0);          // v1 from uniform probs (build-side sums)
    __syncthreads();
    routing_pass();       // logits += prior.v1; sums for iter 2
    __syncthreads();
    finalize(1);          // v2
    __syncthreads();
    routing_pass();       // logits += prior.v2; sums for iter 3
    __syncthreads();
    finalize(2);          // v3 -> out
}

extern "C" void kernel_launch(void* const* d_in, const int* in_sizes, int n_in,
                              void* d_out, int out_size, void* d_ws, size_t ws_size,
                              hipStream_t stream) {
    const float* x = (const float*)d_in[0];
    const float* w = (const float*)d_in[1];
    float* out = (float*)d_out;
    capsule_kernel<<<dim3(NCAP * (NB / TB)), dim3(NT), 0, stream>>>(x, w, out);
}

// Round 8
// 59.932 us; speedup vs baseline: 12.9710x; 1.4085x over previous
//
#include <hip/hip_runtime.h>

#define NCAP 10     // capsule classes c
#define NB   256    // batch b
#define NN   1152   // route nodes n
#define KI   8      // input dim i
#define NO   16     // output dim o
#define NT   1024   // threads per block (16 waves)
#define NWV  16
#define TB   2      // batches per block
#define NITER 3

__global__ __launch_bounds__(NT) void capsule_kernel(
    const float* __restrict__ x,    // [256,1152,8]
    const float* __restrict__ w,    // [10,1152,8,16]
    float* __restrict__ out)        // [10,256,16]
{
    // Priors in LDS as packed bf16 pairs, TRANSPOSED [o_pair][tb][n]:
    //  - 72 KB (vs 144 KB f32 in round 7) -> 2 blocks/CU resident
    //  - routing reads are b32 with bank = n%32: 2 lanes/bank = free
    __shared__ unsigned s_pr[NO/2][TB][NN];   // 73,728 B
    __shared__ float s_red2[NWV][TB][NO];     // per-wave comp partials
    __shared__ float s_ls[NWV][TB];           // per-wave exp-sum partials
    __shared__ float s_v[TB][NO];             // squashed v broadcast

    const int t    = threadIdx.x;
    const int wv   = t >> 6;
    const int lane = t & 63;
    const int j    = t & 3;        // build: o-quad owned by this lane
    const int g    = t >> 2;       // build: cluster id, 0..255

    // XCD swizzle: 1280 % 8 == 0 -> bijective; same-c blocks share an XCD L2.
    const int bid = blockIdx.x;
    const int swz = (bid & 7) * (NCAP * (NB / TB) / 8) + (bid >> 3);
    const int c   = swz / (NB / TB);
    const int b0  = (swz % (NB / TB)) * TB;

    const int bl0 = lane & 1, bl1 = (lane >> 1) & 1,
              bl2 = (lane >> 2) & 1, bl3 = (lane >> 3) & 1;

    // iter-1 weighted sum (softmax(0) uniform) accumulated in f32 during build
    float bs[TB][4] = {{0.f,0.f,0.f,0.f},{0.f,0.f,0.f,0.f}};

    // ---- build: 4-lane cluster per n; lane j computes o-quad j ----
    // W loads stay fully dense: 16 complete contiguous 64B lines / instr.
    auto build_round = [&](int n) {
        const float4* wp = reinterpret_cast<const float4*>(
            w + ((size_t)c * NN + n) * (KI * NO));
        float xs[TB][KI];
        #pragma unroll
        for (int tb = 0; tb < TB; ++tb) {
            const float4* xp = reinterpret_cast<const float4*>(
                x + ((size_t)(b0 + tb) * NN + n) * KI);
            float4 a = xp[0], b = xp[1];   // same addr across cluster -> bcast
            xs[tb][0]=a.x; xs[tb][1]=a.y; xs[tb][2]=a.z; xs[tb][3]=a.w;
            xs[tb][4]=b.x; xs[tb][5]=b.y; xs[tb][6]=b.z; xs[tb][7]=b.w;
        }
        float acc[TB][4] = {{0.f,0.f,0.f,0.f},{0.f,0.f,0.f,0.f}};
        #pragma unroll
        for (int i = 0; i < KI; ++i) {
            float4 wq = wp[i * 4 + j];
            #pragma unroll
            for (int tb = 0; tb < TB; ++tb) {
                acc[tb][0] = fmaf(xs[tb][i], wq.x, acc[tb][0]);
                acc[tb][1] = fmaf(xs[tb][i], wq.y, acc[tb][1]);
                acc[tb][2] = fmaf(xs[tb][i], wq.z, acc[tb][2]);
                acc[tb][3] = fmaf(xs[tb][i], wq.w, acc[tb][3]);
            }
        }
        #pragma unroll
        for (int tb = 0; tb < TB; ++tb) {
            bs[tb][0] += acc[tb][0]; bs[tb][1] += acc[tb][1];
            bs[tb][2] += acc[tb][2]; bs[tb][3] += acc[tb][3];
            unsigned p0, p1;   // pair p: o=2p in lo16, o=2p+1 in hi16 (RNE)
            asm("v_cvt_pk_bf16_f32 %0, %1, %2"
                : "=v"(p0) : "v"(acc[tb][0]), "v"(acc[tb][1]));
            asm("v_cvt_pk_bf16_f32 %0, %1, %2"
                : "=v"(p1) : "v"(acc[tb][2]), "v"(acc[tb][3]));
            s_pr[2*j+0][tb][n] = p0;
            s_pr[2*j+1][tb][n] = p1;
        }
    };
    #pragma unroll 1
    for (int r = 0; r < 4; ++r) build_round(r * 256 + g);
    if (g < 128) build_round(1024 + g);      // wave-uniform (t < 512)

    // reduce bs across the wave's 16 clusters (same j): lanes 0..3 write
    #pragma unroll
    for (int tb = 0; tb < TB; ++tb)
        #pragma unroll
        for (int k = 0; k < 4; ++k) {
            float s = bs[tb][k];
            s += __shfl_xor(s, 4);  s += __shfl_xor(s, 8);
            s += __shfl_xor(s, 16); s += __shfl_xor(s, 32);
            bs[tb][k] = s;
        }
    if (lane < 4) {
        #pragma unroll
        for (int tb = 0; tb < TB; ++tb) {
            s_red2[wv][tb][4*lane+0] = bs[tb][0];
            s_red2[wv][tb][4*lane+1] = bs[tb][1];
            s_red2[wv][tb][4*lane+2] = bs[tb][2];
            s_red2[wv][tb][4*lane+3] = bs[tb][3];
        }
    }
    __syncthreads();

    // ---- finalize: combine waves, softmax-normalize, squash ----
    auto finalize = [&](int iter) {
        if (t < TB * NO) {
            const int tb = t >> 4, oc = t & 15;
            float acc = 0.f, lt = 0.f;
            #pragma unroll
            for (int w2 = 0; w2 < NWV; ++w2) {
                acc += s_red2[w2][tb][oc];
                if (iter > 0) lt += s_ls[w2][tb];
            }
            if (iter == 0) lt = (float)NN;   // softmax(0) is uniform
            float s_o = acc / lt;
            float sq = s_o * s_o;
            sq += __shfl_xor(sq, 1); sq += __shfl_xor(sq, 2);
            sq += __shfl_xor(sq, 4); sq += __shfl_xor(sq, 8);
            float scale = sq / ((1.f + sq) * sqrtf(sq));
            float vo = s_o * scale;
            s_v[tb][oc] = vo;
            if (iter == NITER - 1)
                out[((size_t)c * NB + b0 + tb) * NO + oc] = vo;
        }
    };

    // consumption: thread owns n=t (and 1024+t if t<128) -> private logits;
    // delta + exp + weighted-sum fused in ONE pass over the bf16 priors.
    float logit[2][TB] = {{0.f,0.f},{0.f,0.f}};

    auto routing_pass = [&]() {
        #pragma unroll
        for (int tb = 0; tb < TB; ++tb) {
            float vv[NO];
            {
                const float4* vp = reinterpret_cast<const float4*>(&s_v[tb][0]);
                float4 a = vp[0], b = vp[1], cc = vp[2], d4 = vp[3];
                vv[0]=a.x;  vv[1]=a.y;  vv[2]=a.z;  vv[3]=a.w;
                vv[4]=b.x;  vv[5]=b.y;  vv[6]=b.z;  vv[7]=b.w;
                vv[8]=cc.x; vv[9]=cc.y; vv[10]=cc.z; vv[11]=cc.w;
                vv[12]=d4.x; vv[13]=d4.y; vv[14]=d4.z; vv[15]=d4.w;
            }
            float sp[NO];
            #pragma unroll
            for (int o = 0; o < NO; ++o) sp[o] = 0.f;
            float lse = 0.f;
            #pragma unroll
            for (int rr = 0; rr < 2; ++rr) {
                if (rr == 1 && t >= 128) continue;   // wave-uniform
                const int n = rr * 1024 + t;
                unsigned u[8];
                #pragma unroll
                for (int op = 0; op < 8; ++op) u[op] = s_pr[op][tb][n];
                float d = 0.f;
                #pragma unroll
                for (int op = 0; op < 8; ++op) {
                    float lo = __uint_as_float(u[op] << 16);
                    float hi = __uint_as_float(u[op] & 0xffff0000u);
                    d = fmaf(lo, vv[2*op+0], d);
                    d = fmaf(hi, vv[2*op+1], d);
                }
                logit[rr][tb] += d;        // |logit| <~ 30: fp32 exact-safe
                float e = __expf(logit[rr][tb]);
                lse += e;
                #pragma unroll
                for (int op = 0; op < 8; ++op) {
                    float lo = __uint_as_float(u[op] << 16);
                    float hi = __uint_as_float(u[op] & 0xffff0000u);
                    sp[2*op+0] = fmaf(e, lo, sp[2*op+0]);
                    sp[2*op+1] = fmaf(e, hi, sp[2*op+1]);
                }
            }
            // exp-sum: full-wave butterfly
            float s = lse;
            s += __shfl_xor(s, 1);  s += __shfl_xor(s, 2);
            s += __shfl_xor(s, 4);  s += __shfl_xor(s, 8);
            s += __shfl_xor(s, 16); s += __shfl_xor(s, 32);
            if (lane == 0) s_ls[wv][tb] = s;
            // comp-halving fold: 16 comps over 16-lane groups in 15 shuffles
            float g8[8];
            #pragma unroll
            for (int r = 0; r < 8; ++r) {
                float keep = bl0 ? sp[2*r+1] : sp[2*r];
                float send = bl0 ? sp[2*r]   : sp[2*r+1];
                g8[r] = keep + __shfl_xor(send, 1);
            }
            float g4[4];
            #pragma unroll
            for (int r = 0; r < 4; ++r) {
                float keep = bl1 ? g8[2*r+1] : g8[2*r];
                float send = bl1 ? g8[2*r]   : g8[2*r+1];
                g4[r] = keep + __shfl_xor(send, 2);
            }
            float g2[2];
            #pragma unroll
            for (int r = 0; r < 2; ++r) {
                float keep = bl2 ? g4[2*r+1] : g4[2*r];
                float send = bl2 ? g4[2*r]   : g4[2*r+1];
                g2[r] = keep + __shfl_xor(send, 4);
            }
            float g1;
            {
                float keep = bl3 ? g2[1] : g2[0];
                float send = bl3 ? g2[0] : g2[1];
                g1 = keep + __shfl_xor(send, 8);
            }
            g1 += __shfl_xor(g1, 16);
            g1 += __shfl_xor(g1, 32);
            if (lane < NO) s_red2[wv][tb][lane] = g1;
        }
    };

    finalize(0);          // v1 from uniform probs (build-side f32 sums)
    __syncthreads();
    routing_pass();       // logits += prior.v1; sums for iter 2
    __syncthreads();
    finalize(1);          // v2
    __syncthreads();
    routing_pass();       // logits += prior.v2; sums for iter 3
    __syncthreads();
    finalize(2);          // v3 -> out
}

extern "C" void kernel_launch(void* const* d_in, const int* in_sizes, int n_in,
                              void* d_out, int out_size, void* d_ws, size_t ws_size,
                              hipStream_t stream) {
    const float* x = (const float*)d_in[0];
    const float* w = (const float*)d_in[1];
    float* out = (float*)d_out;
    capsule_kernel<<<dim3(NCAP * (NB / TB)), dim3(NT), 0, stream>>>(x, w, out);
}